// Round 1
// baseline (4857.602 us; speedup 1.0000x reference)
//
#include <hip/hip_runtime.h>

// ---------------------------------------------------------------------------
// MashDecoderV2: 256-layer mamba stack (L=400, D=40) + 65536-query cross-attn
// decoder. f32 throughout (reference is f32; threshold 1.56e-2 absolute).
//
// Stage 1: layer-pipelined persistent kernel. 1 workgroup per layer (grid=256,
//   320 threads). Chunks of 4 tokens flow down the layer chain through two
//   ping-pong global buffers; handoff via device-scope acquire/release flags.
//   Safe without cooperative launch: 63KB LDS/WG -> >=2 WG/CU capacity, so all
//   256 WGs are resident immediately; only layer 0 starts unblocked.
// Stage 2: one thread per query; online-softmax attention over 400 k/v rows
//   (wave-uniform global reads -> scalar cache), FFN with exact-erf GELU.
// ---------------------------------------------------------------------------

#define CH 4
#define NCHUNK 100       // 400 / CH
#define TPB1 320

__global__ void init_flags(int* __restrict__ flags) {
  int i = blockIdx.x * 256 + threadIdx.x;
  if (i < 256 * 16) flags[i] = 0;
}

__global__ __launch_bounds__(TPB1) void mamba_pipe(
    const float* __restrict__ mash,
    const float* __restrict__ g_norm_w,   // (256,40)
    const float* __restrict__ g_in_w,     // (256,160,40)
    const float* __restrict__ g_conv_w,   // (256,80,4)
    const float* __restrict__ g_conv_b,   // (256,80)
    const float* __restrict__ g_xp_w,     // (256,35,80)
    const float* __restrict__ g_dt_w,     // (256,80,3)
    const float* __restrict__ g_dt_b,     // (256,80)
    const float* __restrict__ g_alog,     // (256,80,16)
    const float* __restrict__ g_D,        // (256,80)
    const float* __restrict__ g_out_w,    // (256,40,80)
    float* __restrict__ xb0,
    float* __restrict__ xb1,
    int* __restrict__ flags)
{
  const int layer = blockIdx.x;
  const int tid = threadIdx.x;

  // weights in LDS, leading dims padded to odd strides (bank-conflict-free)
  __shared__ float w_in[160 * 41];
  __shared__ float w_xp[35 * 81];
  __shared__ float w_out[40 * 81];
  __shared__ float w_conv[80 * 5];
  __shared__ float b_conv[80];
  __shared__ float w_dt[240];
  __shared__ float b_dt[80];
  __shared__ float w_nrm[40];
  __shared__ float w_D[80];
  // per-chunk tiles
  __shared__ float xin[CH * 40];
  __shared__ float uu[CH * 40];
  __shared__ float xz[CH * 160];
  __shared__ float xhist[3 * 80];   // conv tail: last 3 x-half tokens
  __shared__ float xs[CH * 80];     // post conv+silu
  __shared__ float dbc[CH * 35];
  __shared__ float dtv[CH * 80];
  __shared__ float yb[CH * 80];

  for (int i = tid; i < 160 * 40; i += TPB1) w_in[(i / 40) * 41 + (i % 40)] = g_in_w[layer * 6400 + i];
  for (int i = tid; i < 35 * 80; i += TPB1) w_xp[(i / 80) * 81 + (i % 80)] = g_xp_w[layer * 2800 + i];
  for (int i = tid; i < 40 * 80; i += TPB1) w_out[(i / 80) * 81 + (i % 80)] = g_out_w[layer * 3200 + i];
  for (int i = tid; i < 320; i += TPB1) w_conv[(i / 4) * 5 + (i % 4)] = g_conv_w[layer * 320 + i];
  for (int i = tid; i < 240; i += TPB1) w_dt[i] = g_dt_w[layer * 240 + i];
  for (int i = tid; i < 80; i += TPB1) {
    b_conv[i] = g_conv_b[layer * 80 + i];
    b_dt[i] = g_dt_b[layer * 80 + i];
    w_D[i] = g_D[layer * 80 + i];
  }
  for (int i = tid; i < 40; i += TPB1) w_nrm[i] = g_norm_w[layer * 40 + i];
  for (int i = tid; i < 240; i += TPB1) xhist[i] = 0.f;

  // scan channel ownership: thread = (d, s-quad); h state lives in registers
  const int d_ch = tid >> 2;     // 0..79
  const int qq = tid & 3;        // s-quad
  float negA[4], hst[4];
#pragma unroll
  for (int j = 0; j < 4; ++j) {
    negA[j] = -__expf(g_alog[layer * 1280 + tid * 4 + j]);  // tid*4+j == d*16+qq*4+j
    hst[j] = 0.f;
  }
  __syncthreads();

  float* xcur = (layer & 1) ? xb1 : xb0;
  const float* xprev = (layer & 1) ? xb0 : xb1;
  const float* src = (layer == 0) ? mash : xprev;
  int* flag_prev = flags + (layer - 1) * 16;
  int* flag_cur = flags + layer * 16;

  for (int c = 0; c < NCHUNK; ++c) {
    const int t0 = c * CH;
    // ---- wait for producer (device-scope acquire) ----
    if (layer > 0) {
      while (__hip_atomic_load(flag_prev, __ATOMIC_RELAXED, __HIP_MEMORY_SCOPE_AGENT) <= c)
        __builtin_amdgcn_s_sleep(1);
      (void)__hip_atomic_load(flag_prev, __ATOMIC_ACQUIRE, __HIP_MEMORY_SCOPE_AGENT);
    }
    __syncthreads();
    // ---- load residual-stream chunk ----
    if (tid < CH * 40) xin[tid] = src[t0 * 40 + tid];
    __syncthreads();
    // ---- rmsnorm (redundant per-element sumsq; 40 MACs, cheap) ----
    if (tid < CH * 40) {
      int t = tid / 40, d = tid % 40;
      float ss = 0.f;
#pragma unroll
      for (int k = 0; k < 40; ++k) { float v = xin[t * 40 + k]; ss += v * v; }
      uu[tid] = xin[tid] * rsqrtf(ss * (1.f / 40.f) + 1e-5f) * w_nrm[d];
    }
    __syncthreads();
    // ---- in_proj: xz[t][e] = in_w[e][:] . u[t][:] ----
    for (int i = tid; i < CH * 160; i += TPB1) {
      int t = i / 160, e = i % 160;
      const float* wr = &w_in[e * 41];
      const float* ur = &uu[t * 40];
      float s = 0.f;
#pragma unroll
      for (int d = 0; d < 40; ++d) s += wr[d] * ur[d];
      xz[i] = s;
    }
    __syncthreads();
    // ---- causal depthwise conv(4) + silu ----
    if (tid < CH * 80) {
      int t = tid / 80, d = tid % 80;
      float acc = b_conv[d];
#pragma unroll
      for (int j = 0; j < 4; ++j) {
        int lt = t - 3 + j;
        float xv;
        if (lt >= 0) xv = xz[lt * 160 + d];
        else xv = (t0 + lt >= 0) ? xhist[(lt + 3) * 80 + d] : 0.f;
        acc += w_conv[d * 5 + j] * xv;
      }
      xs[tid] = acc / (1.f + __expf(-acc));
    }
    __syncthreads();
    // ---- x_proj: dbc[t][e] (e<35: 3 dt-rank, 16 B, 16 C) ----
    if (tid < CH * 35) {
      int t = tid / 35, e = tid % 35;
      const float* wr = &w_xp[e * 81];
      const float* xr = &xs[t * 80];
      float s = 0.f;
#pragma unroll
      for (int d = 0; d < 80; ++d) s += wr[d] * xr[d];
      dbc[tid] = s;
    }
    __syncthreads();
    // ---- dt = softplus(dtr . dt_w + dt_b) ----
    if (tid < CH * 80) {
      int t = tid / 80, d = tid % 80;
      float s = b_dt[d] + dbc[t * 35 + 0] * w_dt[d * 3 + 0]
                        + dbc[t * 35 + 1] * w_dt[d * 3 + 1]
                        + dbc[t * 35 + 2] * w_dt[d * 3 + 2];
      dtv[tid] = (s > 20.f) ? s : log1pf(__expf(s));
    }
    __syncthreads();
    // ---- selective scan (register state, quad shuffle reduce over s) ----
#pragma unroll
    for (int t = 0; t < CH; ++t) {
      float dtval = dtv[t * 80 + d_ch];
      float xval = xs[t * 80 + d_ch];
      float part = 0.f;
#pragma unroll
      for (int j = 0; j < 4; ++j) {
        int s_i = qq * 4 + j;
        float Bv = dbc[t * 35 + 3 + s_i];
        float Cv = dbc[t * 35 + 19 + s_i];
        hst[j] = __expf(dtval * negA[j]) * hst[j] + dtval * Bv * xval;
        part += hst[j] * Cv;
      }
      part += __shfl_xor(part, 1);
      part += __shfl_xor(part, 2);
      if (qq == 0) {
        float yv = part + xval * w_D[d_ch];
        float z = xz[t * 160 + 80 + d_ch];
        yv *= z / (1.f + __expf(-z));          // gate by silu(z)
        yb[t * 80 + d_ch] = yv;
      }
    }
    __syncthreads();
    // ---- out_proj + residual; refresh conv history ----
    for (int i = tid; i < CH * 40 + 240; i += TPB1) {
      if (i < CH * 40) {
        int t = i / 40;
        const float* wr = &w_out[(i % 40) * 81];
        const float* yr = &yb[t * 80];
        float s = xin[i];
#pragma unroll
        for (int d = 0; d < 80; ++d) s += wr[d] * yr[d];
        xcur[t0 * 40 + i] = s;
      } else {
        int k = i - CH * 40;                     // 0..239
        xhist[k] = xz[(CH - 3 + k / 80) * 160 + (k % 80)];
      }
    }
    __threadfence();      // make this chunk's global stores agent-visible
    __syncthreads();
    if (tid == 0)
      __hip_atomic_store(flag_cur, c + 1, __ATOMIC_RELEASE, __HIP_MEMORY_SCOPE_AGENT);
  }
}

// ---- context side of cross-attn: cn = LN(x_final), kv = cn @ ca_kv_w^T ----
__global__ __launch_bounds__(64) void kv_kernel(
    const float* __restrict__ xfin,
    const float* __restrict__ lnc_w, const float* __restrict__ lnc_b,
    const float* __restrict__ kv_w,
    float* __restrict__ kbuf, float* __restrict__ vbuf)
{
  int t = blockIdx.x;
  int lane = threadIdx.x;
  float x = (lane < 40) ? xfin[t * 40 + lane] : 0.f;
  float s = x;
#pragma unroll
  for (int o = 32; o >= 1; o >>= 1) s += __shfl_xor(s, o);
  float m = s * (1.f / 40.f);
  float dv = (lane < 40) ? (x - m) : 0.f;
  float v2 = dv * dv;
#pragma unroll
  for (int o = 32; o >= 1; o >>= 1) v2 += __shfl_xor(v2, o);
  float rstd = rsqrtf(v2 * (1.f / 40.f) + 1e-5f);
  __shared__ float cn[40];
  if (lane < 40) cn[lane] = dv * rstd * lnc_w[lane] + lnc_b[lane];
  __syncthreads();
  for (int e = lane; e < 80; e += 64) {
    float acc = 0.f;
#pragma unroll
    for (int d = 0; d < 40; ++d) acc += cn[d] * kv_w[e * 40 + d];
    if (e < 40) kbuf[t * 40 + e] = acc;
    else vbuf[t * 40 + (e - 40)] = acc;
  }
}

// ---- per-query decode: PE-MLP, LN, q, flash-attn over 400, FFN, occ ----
__global__ __launch_bounds__(256) void query_kernel(
    const float* __restrict__ qry,
    const float* __restrict__ pe_w, const float* __restrict__ pe_b,
    const float* __restrict__ lnq_w, const float* __restrict__ lnq_b,
    const float* __restrict__ qw,
    const float* __restrict__ ow, const float* __restrict__ ob,
    const float* __restrict__ flw, const float* __restrict__ flb,
    const float* __restrict__ w1, const float* __restrict__ b1,
    const float* __restrict__ w2, const float* __restrict__ b2,
    const float* __restrict__ outw, const float* __restrict__ outb,
    const float* __restrict__ kbuf, const float* __restrict__ vbuf,
    float* __restrict__ out)
{
  const int tid = threadIdx.x;
  const int n = blockIdx.x * 256 + tid;
  __shared__ float vbufA[40 * 256];   // per-thread 40-vec staging (own column)

  const float qx = qry[n * 3 + 0], qy = qry[n * 3 + 1], qz = qry[n * 3 + 2];

  // positional-encoding MLP: qe[d] = pe_b[d] + sum_f pe[f]*W[d][f]
  float qe[40];
#pragma unroll
  for (int d = 0; d < 40; ++d) qe[d] = pe_b[d];
#pragma unroll 1
  for (int j = 0; j < 8; ++j) {
    float f = 3.14159265358979323846f * (float)(1 << j);
    float sx, cx, sy, cy, sz, cz;
    sincosf(qx * f, &sx, &cx);
    sincosf(qy * f, &sy, &cy);
    sincosf(qz * f, &sz, &cz);
#pragma unroll
    for (int d = 0; d < 40; ++d) {
      const float* r = pe_w + d * 51;
      qe[d] += sx * r[j] + sy * r[j + 8] + sz * r[j + 16]
             + cx * r[j + 24] + cy * r[j + 32] + cz * r[j + 40];
    }
  }
#pragma unroll
  for (int d = 0; d < 40; ++d) {
    const float* r = pe_w + d * 51;
    qe[d] += qx * r[48] + qy * r[49] + qz * r[50];
  }

  // layernorm(qe) -> LDS column (needed with dynamic index for q-proj)
  {
    float m = 0.f;
#pragma unroll
    for (int d = 0; d < 40; ++d) m += qe[d];
    m *= (1.f / 40.f);
    float var = 0.f;
#pragma unroll
    for (int d = 0; d < 40; ++d) { float dv = qe[d] - m; var += dv * dv; }
    float rstd = rsqrtf(var * (1.f / 40.f) + 1e-5f);
#pragma unroll
    for (int d = 0; d < 40; ++d)
      vbufA[d * 256 + tid] = (qe[d] - m) * rstd * lnq_w[d] + lnq_b[d];
  }

  // q = qn @ ca_q_w^T   (q in regs for the flash loop)
  float q[40];
#pragma unroll
  for (int e = 0; e < 40; ++e) q[e] = 0.f;
#pragma unroll 1
  for (int d = 0; d < 40; ++d) {
    float qv = vbufA[d * 256 + tid];
#pragma unroll
    for (int e = 0; e < 40; ++e) q[e] += qv * qw[e * 40 + d];
  }

  // online-softmax attention over 400 context tokens (k/v wave-uniform reads)
  float acc[40];
#pragma unroll
  for (int d = 0; d < 40; ++d) acc[d] = 0.f;
  float mx = -1e30f, l = 0.f;
  const float scale = 0.15811388300841897f;  // 40^-0.5
#pragma unroll 1
  for (int t = 0; t < 400; ++t) {
    const float* kr = kbuf + t * 40;
    float s0 = 0.f, s1 = 0.f, s2 = 0.f, s3 = 0.f;
#pragma unroll
    for (int d = 0; d < 40; d += 4) {
      s0 += q[d] * kr[d];
      s1 += q[d + 1] * kr[d + 1];
      s2 += q[d + 2] * kr[d + 2];
      s3 += q[d + 3] * kr[d + 3];
    }
    float s = ((s0 + s1) + (s2 + s3)) * scale;
    if (s > mx) {
      float corr = __expf(mx - s);
      l *= corr;
#pragma unroll
      for (int d = 0; d < 40; ++d) acc[d] *= corr;
      mx = s;
    }
    float p = __expf(s - mx);
    l += p;
    const float* vr = vbuf + t * 40;
#pragma unroll
    for (int d = 0; d < 40; ++d) acc[d] += p * vr[d];
  }
  float linv = 1.f / l;
#pragma unroll
  for (int d = 0; d < 40; ++d) vbufA[d * 256 + tid] = acc[d] * linv;

  // lat2 = lat @ ca_out_w^T + ob
  float lat2[40];
#pragma unroll
  for (int e = 0; e < 40; ++e) lat2[e] = ob[e];
#pragma unroll 1
  for (int d = 0; d < 40; ++d) {
    float lv = vbufA[d * 256 + tid];
#pragma unroll
    for (int e = 0; e < 40; ++e) lat2[e] += lv * ow[e * 40 + d];
  }

  // h = LN(lat2)
  float h[40];
  {
    float m = 0.f;
#pragma unroll
    for (int d = 0; d < 40; ++d) m += lat2[d];
    m *= (1.f / 40.f);
    float var = 0.f;
#pragma unroll
    for (int d = 0; d < 40; ++d) { float dv = lat2[d] - m; var += dv * dv; }
    float rstd = rsqrtf(var * (1.f / 40.f) + 1e-5f);
#pragma unroll
    for (int d = 0; d < 40; ++d) h[d] = (lat2[d] - m) * rstd * flw[d] + flb[d];
  }

  // FFN: geglu-ish split, exact-erf gelu, accumulate ff[d] per e
  float ff[40];
#pragma unroll
  for (int d = 0; d < 40; ++d) ff[d] = b2[d];
#pragma unroll 1
  for (int e = 0; e < 160; ++e) {
    const float* r1 = w1 + e * 40;
    const float* r2 = w1 + (160 + e) * 40;
    float a0 = 0.f, a1 = 0.f;
#pragma unroll
    for (int d = 0; d < 40; ++d) { a0 += h[d] * r1[d]; a1 += h[d] * r2[d]; }
    float x1 = a0 + b1[e];
    float g = a1 + b1[160 + e];
    float tv = x1 * (0.5f * g * (1.f + erff(g * 0.70710678118654752f)));
#pragma unroll
    for (int d = 0; d < 40; ++d) ff[d] += tv * w2[d * 160 + e];
  }

  float r = outb[0];
#pragma unroll
  for (int d = 0; d < 40; ++d) r += (lat2[d] + ff[d]) * outw[d];
  out[n] = r;
}

extern "C" void kernel_launch(void* const* d_in, const int* in_sizes, int n_in,
                              void* d_out, int out_size, void* d_ws, size_t ws_size,
                              hipStream_t stream) {
  const float* mash   = (const float*)d_in[0];
  const float* qry    = (const float*)d_in[1];
  const float* lnw    = (const float*)d_in[2];
  const float* linw   = (const float*)d_in[3];
  const float* lconvw = (const float*)d_in[4];
  const float* lconvb = (const float*)d_in[5];
  const float* lxpw   = (const float*)d_in[6];
  const float* ldtw   = (const float*)d_in[7];
  const float* ldtb   = (const float*)d_in[8];
  const float* lAlog  = (const float*)d_in[9];
  const float* lD     = (const float*)d_in[10];
  const float* loutw  = (const float*)d_in[11];
  const float* pew    = (const float*)d_in[12];
  const float* peb    = (const float*)d_in[13];
  const float* lnqw   = (const float*)d_in[14];
  const float* lnqb   = (const float*)d_in[15];
  const float* lncw   = (const float*)d_in[16];
  const float* lncb   = (const float*)d_in[17];
  const float* qw     = (const float*)d_in[18];
  const float* kvw    = (const float*)d_in[19];
  const float* oww    = (const float*)d_in[20];
  const float* owb    = (const float*)d_in[21];
  const float* flnw   = (const float*)d_in[22];
  const float* flnb   = (const float*)d_in[23];
  const float* w1     = (const float*)d_in[24];
  const float* b1     = (const float*)d_in[25];
  const float* w2     = (const float*)d_in[26];
  const float* b2     = (const float*)d_in[27];
  const float* outw   = (const float*)d_in[28];
  const float* outb   = (const float*)d_in[29];

  // ws layout (f32 elements): xb0[16000] xb1[16000] k[16000] v[16000] flags
  float* wsf = (float*)d_ws;
  float* xb0 = wsf;
  float* xb1 = wsf + 16000;
  float* kbuf = wsf + 32000;
  float* vbuf = wsf + 48000;
  int* flags = (int*)(wsf + 64000);   // 256*16 ints; total ws use ~272 KB

  hipLaunchKernelGGL(init_flags, dim3(16), dim3(256), 0, stream, flags);
  hipLaunchKernelGGL(mamba_pipe, dim3(256), dim3(TPB1), 0, stream,
                     mash, lnw, linw, lconvw, lconvb, lxpw, ldtw, ldtb, lAlog,
                     lD, loutw, xb0, xb1, flags);
  // layer 255 writes xb1 ((255&1)==1)
  hipLaunchKernelGGL(kv_kernel, dim3(400), dim3(64), 0, stream,
                     xb1, lncw, lncb, kvw, kbuf, vbuf);
  hipLaunchKernelGGL(query_kernel, dim3(256), dim3(256), 0, stream,
                     qry, pew, peb, lnqw, lnqb, qw, oww, owb, flnw, flnb,
                     w1, b1, w2, b2, outw, outb, kbuf, vbuf, (float*)d_out);
}

// Round 2
// 3302.802 us; speedup vs baseline: 1.4708x; 1.4708x over previous
//
#include <hip/hip_runtime.h>

// ---------------------------------------------------------------------------
// MashDecoderV2: 256-layer mamba stack (L=400, D=40) + 65536-query cross-attn
// decoder. f32 throughout (threshold 1.56e-2 absolute; round-0 absmax 2e-3).
//
// Stage 1: layer-pipelined persistent kernel, 1 WG/layer, 320 threads.
//   Handoff protocol (round-1 change): chunk data + flags go through the
//   Infinity-Cache coherence point via relaxed AGENT-scope atomics (sc1
//   write-through stores / cache-bypassing loads). NO release/acquire fences
//   -> NO buffer_wbl2 / buffer_inv L2 flushes (round-0's 11.5us/stage cost).
//   Ordering: producer's __syncthreads() drains vmcnt of all waves before the
//   flag store; consumer's data loads are issued only after the flag poll
//   (branch-resolved) + barrier, and sc1 loads cannot hit stale caches.
// Stage 2: 2 threads per query (2 waves/SIMD), half the flash loop each,
//   online-softmax state merged via shfl_xor(1); FFN redundant per pair.
// ---------------------------------------------------------------------------

#define CH 4
#define NCHUNK 100       // 400 / CH
#define TPB1 320

__global__ void init_flags(int* __restrict__ flags) {
  int i = blockIdx.x * 256 + threadIdx.x;
  if (i < 256 * 16) flags[i] = 0;
}

__global__ __launch_bounds__(TPB1) void mamba_pipe(
    const float* __restrict__ mash,
    const float* __restrict__ g_norm_w,   // (256,40)
    const float* __restrict__ g_in_w,     // (256,160,40)
    const float* __restrict__ g_conv_w,   // (256,80,4)
    const float* __restrict__ g_conv_b,   // (256,80)
    const float* __restrict__ g_xp_w,     // (256,35,80)
    const float* __restrict__ g_dt_w,     // (256,80,3)
    const float* __restrict__ g_dt_b,     // (256,80)
    const float* __restrict__ g_alog,     // (256,80,16)
    const float* __restrict__ g_D,        // (256,80)
    const float* __restrict__ g_out_w,    // (256,40,80)
    float* __restrict__ xb0,
    float* __restrict__ xb1,
    int* __restrict__ flags)
{
  const int layer = blockIdx.x;
  const int tid = threadIdx.x;

  // weights in LDS, leading dims padded to odd strides (bank-conflict-free)
  __shared__ float w_in[160 * 41];
  __shared__ float w_xp[35 * 81];
  __shared__ float w_out[40 * 81];
  __shared__ float w_conv[80 * 5];
  __shared__ float b_conv[80];
  __shared__ float w_dt[240];
  __shared__ float b_dt[80];
  __shared__ float w_nrm[40];
  __shared__ float w_D[80];
  // per-chunk tiles
  __shared__ float xin[CH * 40];
  __shared__ float uu[CH * 40];
  __shared__ float xz[CH * 160];
  __shared__ float xhist[3 * 80];   // conv tail: last 3 x-half tokens
  __shared__ float xs[CH * 80];     // post conv+silu
  __shared__ float dbc[CH * 35];
  __shared__ float yb[CH * 80];

  for (int i = tid; i < 160 * 40; i += TPB1) w_in[(i / 40) * 41 + (i % 40)] = g_in_w[layer * 6400 + i];
  for (int i = tid; i < 35 * 80; i += TPB1) w_xp[(i / 80) * 81 + (i % 80)] = g_xp_w[layer * 2800 + i];
  for (int i = tid; i < 40 * 80; i += TPB1) w_out[(i / 80) * 81 + (i % 80)] = g_out_w[layer * 3200 + i];
  for (int i = tid; i < 320; i += TPB1) w_conv[(i / 4) * 5 + (i % 4)] = g_conv_w[layer * 320 + i];
  for (int i = tid; i < 240; i += TPB1) w_dt[i] = g_dt_w[layer * 240 + i];
  for (int i = tid; i < 80; i += TPB1) {
    b_conv[i] = g_conv_b[layer * 80 + i];
    b_dt[i] = g_dt_b[layer * 80 + i];
    w_D[i] = g_D[layer * 80 + i];
  }
  for (int i = tid; i < 40; i += TPB1) w_nrm[i] = g_norm_w[layer * 40 + i];
  for (int i = tid; i < 240; i += TPB1) xhist[i] = 0.f;

  // scan channel ownership: thread = (d, s-quad); h state lives in registers
  const int d_ch = tid >> 2;     // 0..79
  const int qq = tid & 3;        // s-quad
  float negA[4], hst[4];
#pragma unroll
  for (int j = 0; j < 4; ++j) {
    negA[j] = -__expf(g_alog[layer * 1280 + tid * 4 + j]);  // tid*4+j == d*16+qq*4+j
    hst[j] = 0.f;
  }
  __syncthreads();

  float* xcur = (layer & 1) ? xb1 : xb0;
  const float* xprev = (layer & 1) ? xb0 : xb1;
  const float* src = (layer == 0) ? mash : xprev;
  int* flag_prev = flags + (layer - 1) * 16;
  int* flag_cur = flags + layer * 16;

  for (int c = 0; c < NCHUNK; ++c) {
    const int t0 = c * CH;
    // ---- wait for producer: single-thread relaxed poll, NO acquire fence ----
    if (layer > 0 && tid == 0) {
      while (__hip_atomic_load(flag_prev, __ATOMIC_RELAXED, __HIP_MEMORY_SCOPE_AGENT) <= c)
        __builtin_amdgcn_s_sleep(1);
    }
    __syncthreads();
    // ---- load residual-stream chunk via IF$-coherent (sc1) loads ----
    if (tid < CH * 40)
      xin[tid] = __hip_atomic_load(&src[t0 * 40 + tid], __ATOMIC_RELAXED,
                                   __HIP_MEMORY_SCOPE_AGENT);
    __syncthreads();
    // ---- rmsnorm (redundant per-element sumsq; 40 MACs, cheap) ----
    if (tid < CH * 40) {
      int t = tid / 40, d = tid % 40;
      float ss = 0.f;
#pragma unroll
      for (int k = 0; k < 40; ++k) { float v = xin[t * 40 + k]; ss += v * v; }
      uu[tid] = xin[tid] * rsqrtf(ss * (1.f / 40.f) + 1e-5f) * w_nrm[d];
    }
    __syncthreads();
    // ---- in_proj: xz[t][e] = in_w[e][:] . u[t][:] ----
    for (int i = tid; i < CH * 160; i += TPB1) {
      int t = i / 160, e = i % 160;
      const float* wr = &w_in[e * 41];
      const float* ur = &uu[t * 40];
      float s = 0.f;
#pragma unroll
      for (int d = 0; d < 40; ++d) s += wr[d] * ur[d];
      xz[i] = s;
    }
    __syncthreads();
    // ---- causal depthwise conv(4) + silu ----
    if (tid < CH * 80) {
      int t = tid / 80, d = tid % 80;
      float acc = b_conv[d];
#pragma unroll
      for (int j = 0; j < 4; ++j) {
        int lt = t - 3 + j;
        float xv;
        if (lt >= 0) xv = xz[lt * 160 + d];
        else xv = (t0 + lt >= 0) ? xhist[(lt + 3) * 80 + d] : 0.f;
        acc += w_conv[d * 5 + j] * xv;
      }
      xs[tid] = acc / (1.f + __expf(-acc));
    }
    __syncthreads();
    // ---- x_proj: dbc[t][e] (e<35: 3 dt-rank, 16 B, 16 C) ----
    if (tid < CH * 35) {
      int t = tid / 35, e = tid % 35;
      const float* wr = &w_xp[e * 81];
      const float* xr = &xs[t * 80];
      float s = 0.f;
#pragma unroll
      for (int d = 0; d < 80; ++d) s += wr[d] * xr[d];
      dbc[tid] = s;
    }
    __syncthreads();
    // ---- selective scan; dt computed inline (redundant per s-quad) ----
#pragma unroll
    for (int t = 0; t < CH; ++t) {
      float sdt = b_dt[d_ch] + dbc[t * 35 + 0] * w_dt[d_ch * 3 + 0]
                             + dbc[t * 35 + 1] * w_dt[d_ch * 3 + 1]
                             + dbc[t * 35 + 2] * w_dt[d_ch * 3 + 2];
      float dtval = (sdt > 20.f) ? sdt : log1pf(__expf(sdt));
      float xval = xs[t * 80 + d_ch];
      float part = 0.f;
#pragma unroll
      for (int j = 0; j < 4; ++j) {
        int s_i = qq * 4 + j;
        float Bv = dbc[t * 35 + 3 + s_i];
        float Cv = dbc[t * 35 + 19 + s_i];
        hst[j] = __expf(dtval * negA[j]) * hst[j] + dtval * Bv * xval;
        part += hst[j] * Cv;
      }
      part += __shfl_xor(part, 1);
      part += __shfl_xor(part, 2);
      if (qq == 0) {
        float yv = part + xval * w_D[d_ch];
        float z = xz[t * 160 + 80 + d_ch];
        yv *= z / (1.f + __expf(-z));          // gate by silu(z)
        yb[t * 80 + d_ch] = yv;
      }
    }
    __syncthreads();
    // ---- out_proj + residual -> IF$-coherent (sc1) stores; conv history ----
    for (int i = tid; i < CH * 40 + 240; i += TPB1) {
      if (i < CH * 40) {
        int t = i / 40;
        const float* wr = &w_out[(i % 40) * 81];
        const float* yr = &yb[t * 80];
        float s = xin[i];
#pragma unroll
        for (int d = 0; d < 80; ++d) s += wr[d] * yr[d];
        __hip_atomic_store(&xcur[t0 * 40 + i], s, __ATOMIC_RELAXED,
                           __HIP_MEMORY_SCOPE_AGENT);
      } else {
        int k = i - CH * 40;                     // 0..239
        xhist[k] = xz[(CH - 3 + k / 80) * 160 + (k % 80)];
      }
    }
    // barrier drains every wave's vmcnt -> all sc1 stores acked at IF$
    __syncthreads();
    if (tid == 0)
      __hip_atomic_store(flag_cur, c + 1, __ATOMIC_RELAXED, __HIP_MEMORY_SCOPE_AGENT);
  }
}

// ---- context side of cross-attn: cn = LN(x_final), kv = cn @ ca_kv_w^T ----
__global__ __launch_bounds__(64) void kv_kernel(
    const float* __restrict__ xfin,
    const float* __restrict__ lnc_w, const float* __restrict__ lnc_b,
    const float* __restrict__ kv_w,
    float* __restrict__ kbuf, float* __restrict__ vbuf)
{
  int t = blockIdx.x;
  int lane = threadIdx.x;
  float x = (lane < 40) ? xfin[t * 40 + lane] : 0.f;
  float s = x;
#pragma unroll
  for (int o = 32; o >= 1; o >>= 1) s += __shfl_xor(s, o);
  float m = s * (1.f / 40.f);
  float dv = (lane < 40) ? (x - m) : 0.f;
  float v2 = dv * dv;
#pragma unroll
  for (int o = 32; o >= 1; o >>= 1) v2 += __shfl_xor(v2, o);
  float rstd = rsqrtf(v2 * (1.f / 40.f) + 1e-5f);
  __shared__ float cn[40];
  if (lane < 40) cn[lane] = dv * rstd * lnc_w[lane] + lnc_b[lane];
  __syncthreads();
  for (int e = lane; e < 80; e += 64) {
    float acc = 0.f;
#pragma unroll
    for (int d = 0; d < 40; ++d) acc += cn[d] * kv_w[e * 40 + d];
    if (e < 40) kbuf[t * 40 + e] = acc;
    else vbuf[t * 40 + (e - 40)] = acc;
  }
}

// ---- per-query decode: 2 threads/query; each runs half the flash loop ----
__global__ __launch_bounds__(256) void query_kernel(
    const float* __restrict__ qry,
    const float* __restrict__ pe_w, const float* __restrict__ pe_b,
    const float* __restrict__ lnq_w, const float* __restrict__ lnq_b,
    const float* __restrict__ qw,
    const float* __restrict__ ow, const float* __restrict__ ob,
    const float* __restrict__ flw, const float* __restrict__ flb,
    const float* __restrict__ w1, const float* __restrict__ b1,
    const float* __restrict__ w2, const float* __restrict__ b2,
    const float* __restrict__ outw, const float* __restrict__ outb,
    const float* __restrict__ kbuf, const float* __restrict__ vbuf,
    float* __restrict__ out)
{
  const int tid = threadIdx.x;
  const int gid = blockIdx.x * 256 + tid;
  const int n = gid >> 1;          // query index
  const int h = gid & 1;           // which half of the 400 tokens
  __shared__ float vbufA[40 * 256];   // per-thread 40-vec staging (own column)

  const float qx = qry[n * 3 + 0], qy = qry[n * 3 + 1], qz = qry[n * 3 + 2];

  // positional-encoding MLP: qe[d] = pe_b[d] + sum_f pe[f]*W[d][f]
  float qe[40];
#pragma unroll
  for (int d = 0; d < 40; ++d) qe[d] = pe_b[d];
#pragma unroll 1
  for (int j = 0; j < 8; ++j) {
    float f = 3.14159265358979323846f * (float)(1 << j);
    float sx, cx, sy, cy, sz, cz;
    __sincosf(qx * f, &sx, &cx);
    __sincosf(qy * f, &sy, &cy);
    __sincosf(qz * f, &sz, &cz);
#pragma unroll
    for (int d = 0; d < 40; ++d) {
      const float* r = pe_w + d * 51;
      qe[d] += sx * r[j] + sy * r[j + 8] + sz * r[j + 16]
             + cx * r[j + 24] + cy * r[j + 32] + cz * r[j + 40];
    }
  }
#pragma unroll
  for (int d = 0; d < 40; ++d) {
    const float* r = pe_w + d * 51;
    qe[d] += qx * r[48] + qy * r[49] + qz * r[50];
  }

  // layernorm(qe) -> LDS column (dynamic index needed for q-proj)
  {
    float m = 0.f;
#pragma unroll
    for (int d = 0; d < 40; ++d) m += qe[d];
    m *= (1.f / 40.f);
    float var = 0.f;
#pragma unroll
    for (int d = 0; d < 40; ++d) { float dv = qe[d] - m; var += dv * dv; }
    float rstd = rsqrtf(var * (1.f / 40.f) + 1e-5f);
#pragma unroll
    for (int d = 0; d < 40; ++d)
      vbufA[d * 256 + tid] = (qe[d] - m) * rstd * lnq_w[d] + lnq_b[d];
  }

  // q = qn @ ca_q_w^T   (q in regs for the flash loop)
  float q[40];
#pragma unroll
  for (int e = 0; e < 40; ++e) q[e] = 0.f;
#pragma unroll 1
  for (int d = 0; d < 40; ++d) {
    float qv = vbufA[d * 256 + tid];
#pragma unroll
    for (int e = 0; e < 40; ++e) q[e] += qv * qw[e * 40 + d];
  }

  // online-softmax attention over this thread's 200 context tokens
  float acc[40];
#pragma unroll
  for (int d = 0; d < 40; ++d) acc[d] = 0.f;
  float mx = -1e30f, l = 0.f;
  const float scale = 0.15811388300841897f;  // 40^-0.5
  const int tbeg = h * 200, tend = tbeg + 200;
#pragma unroll 1
  for (int t = tbeg; t < tend; ++t) {
    const float* kr = kbuf + t * 40;
    float s0 = 0.f, s1 = 0.f, s2 = 0.f, s3 = 0.f;
#pragma unroll
    for (int d = 0; d < 40; d += 4) {
      s0 += q[d] * kr[d];
      s1 += q[d + 1] * kr[d + 1];
      s2 += q[d + 2] * kr[d + 2];
      s3 += q[d + 3] * kr[d + 3];
    }
    float s = ((s0 + s1) + (s2 + s3)) * scale;
    if (s > mx) {
      float corr = __expf(mx - s);
      l *= corr;
#pragma unroll
      for (int d = 0; d < 40; ++d) acc[d] *= corr;
      mx = s;
    }
    float p = __expf(s - mx);
    l += p;
    const float* vr = vbuf + t * 40;
#pragma unroll
    for (int d = 0; d < 40; ++d) acc[d] += p * vr[d];
  }
  // merge the two halves across the lane pair (symmetric -> both lanes full)
  {
    float m2 = __shfl_xor(mx, 1);
    float l2 = __shfl_xor(l, 1);
    float nm = fmaxf(mx, m2);
    float a = __expf(mx - nm), b = __expf(m2 - nm);
    l = l * a + l2 * b;
#pragma unroll
    for (int d = 0; d < 40; ++d)
      acc[d] = acc[d] * a + __shfl_xor(acc[d], 1) * b;
    mx = nm;
  }
  float linv = 1.f / l;
#pragma unroll
  for (int d = 0; d < 40; ++d) vbufA[d * 256 + tid] = acc[d] * linv;

  // lat2 = lat @ ca_out_w^T + ob   (redundant per pair; no divergence)
  float lat2[40];
#pragma unroll
  for (int e = 0; e < 40; ++e) lat2[e] = ob[e];
#pragma unroll 1
  for (int d = 0; d < 40; ++d) {
    float lv = vbufA[d * 256 + tid];
#pragma unroll
    for (int e = 0; e < 40; ++e) lat2[e] += lv * ow[e * 40 + d];
  }

  // h = LN(lat2)
  float hh[40];
  {
    float m = 0.f;
#pragma unroll
    for (int d = 0; d < 40; ++d) m += lat2[d];
    m *= (1.f / 40.f);
    float var = 0.f;
#pragma unroll
    for (int d = 0; d < 40; ++d) { float dv = lat2[d] - m; var += dv * dv; }
    float rstd = rsqrtf(var * (1.f / 40.f) + 1e-5f);
#pragma unroll
    for (int d = 0; d < 40; ++d) hh[d] = (lat2[d] - m) * rstd * flw[d] + flb[d];
  }

  // FFN: split-GLU, exact-erf gelu
  float ff[40];
#pragma unroll
  for (int d = 0; d < 40; ++d) ff[d] = b2[d];
#pragma unroll 1
  for (int e = 0; e < 160; ++e) {
    const float* r1 = w1 + e * 40;
    const float* r2 = w1 + (160 + e) * 40;
    float a0 = 0.f, a1 = 0.f;
#pragma unroll
    for (int d = 0; d < 40; ++d) { a0 += hh[d] * r1[d]; a1 += hh[d] * r2[d]; }
    float x1 = a0 + b1[e];
    float g = a1 + b1[160 + e];
    float tv = x1 * (0.5f * g * (1.f + erff(g * 0.70710678118654752f)));
#pragma unroll
    for (int d = 0; d < 40; ++d) ff[d] += tv * w2[d * 160 + e];
  }

  float r = outb[0];
#pragma unroll
  for (int d = 0; d < 40; ++d) r += (lat2[d] + ff[d]) * outw[d];
  if (h == 0) out[n] = r;
}

extern "C" void kernel_launch(void* const* d_in, const int* in_sizes, int n_in,
                              void* d_out, int out_size, void* d_ws, size_t ws_size,
                              hipStream_t stream) {
  const float* mash   = (const float*)d_in[0];
  const float* qry    = (const float*)d_in[1];
  const float* lnw    = (const float*)d_in[2];
  const float* linw   = (const float*)d_in[3];
  const float* lconvw = (const float*)d_in[4];
  const float* lconvb = (const float*)d_in[5];
  const float* lxpw   = (const float*)d_in[6];
  const float* ldtw   = (const float*)d_in[7];
  const float* ldtb   = (const float*)d_in[8];
  const float* lAlog  = (const float*)d_in[9];
  const float* lD     = (const float*)d_in[10];
  const float* loutw  = (const float*)d_in[11];
  const float* pew    = (const float*)d_in[12];
  const float* peb    = (const float*)d_in[13];
  const float* lnqw   = (const float*)d_in[14];
  const float* lnqb   = (const float*)d_in[15];
  const float* lncw   = (const float*)d_in[16];
  const float* lncb   = (const float*)d_in[17];
  const float* qw     = (const float*)d_in[18];
  const float* kvw    = (const float*)d_in[19];
  const float* oww    = (const float*)d_in[20];
  const float* owb    = (const float*)d_in[21];
  const float* flnw   = (const float*)d_in[22];
  const float* flnb   = (const float*)d_in[23];
  const float* w1     = (const float*)d_in[24];
  const float* b1     = (const float*)d_in[25];
  const float* w2     = (const float*)d_in[26];
  const float* b2     = (const float*)d_in[27];
  const float* outw   = (const float*)d_in[28];
  const float* outb   = (const float*)d_in[29];

  // ws layout (f32 elements): xb0[16000] xb1[16000] k[16000] v[16000] flags
  float* wsf = (float*)d_ws;
  float* xb0 = wsf;
  float* xb1 = wsf + 16000;
  float* kbuf = wsf + 32000;
  float* vbuf = wsf + 48000;
  int* flags = (int*)(wsf + 64000);   // 256*16 ints; total ws use ~272 KB

  hipLaunchKernelGGL(init_flags, dim3(16), dim3(256), 0, stream, flags);
  hipLaunchKernelGGL(mamba_pipe, dim3(256), dim3(TPB1), 0, stream,
                     mash, lnw, linw, lconvw, lconvb, lxpw, ldtw, ldtb, lAlog,
                     lD, loutw, xb0, xb1, flags);
  // layer 255 writes xb1 ((255&1)==1)
  hipLaunchKernelGGL(kv_kernel, dim3(400), dim3(64), 0, stream,
                     xb1, lncw, lncb, kvw, kbuf, vbuf);
  hipLaunchKernelGGL(query_kernel, dim3(512), dim3(256), 0, stream,
                     qry, pew, peb, lnqw, lnqb, qw, oww, owb, flnw, flnb,
                     w1, b1, w2, b2, outw, outb, kbuf, vbuf, (float*)d_out);
}

// Round 3
// 2950.874 us; speedup vs baseline: 1.6462x; 1.1193x over previous
//
#include <hip/hip_runtime.h>

// ---------------------------------------------------------------------------
// MashDecoderV2: 256-layer mamba stack (L=400, D=40) + 65536-query cross-attn
// decoder. f32 throughout (threshold 1.56e-2; current absmax 2e-3).
//
// Stage 1: layer-pipelined persistent kernel, 1 WG/layer, 320 threads.
//   Round-2 protocol kept: IF$-coherent relaxed agent atomics for data+flags,
//   no acquire/release fences (no L2 writeback/invalidate storms).
//   Round-3 change: WEIGHT-STATIONARY REGISTERS. Each thread owns its matvec
//   rows in VGPRs (loaded once); LDS holds only activations, read as float4
//   with <=2 distinct addresses per wave (broadcast, conflict-free). Round-2
//   was LDS-issue-bound (2 scalar ds_read per MAC -> ~4us/chunk of LDS issue).
// Stage 2: 2 threads/query; PE/q-proj/lat2/FFN split across the pair and
//   merged via shfl_xor(1); float4 k/v loads in the flash loop.
// ---------------------------------------------------------------------------

#define CH 4
#define NCHUNK 100       // 400 / CH
#define TPB1 320

__global__ void init_flags(int* __restrict__ flags) {
  int i = blockIdx.x * 256 + threadIdx.x;
  if (i < 256 * 16) flags[i] = 0;
}

__global__ __launch_bounds__(TPB1) void mamba_pipe(
    const float* __restrict__ mash,
    const float* __restrict__ g_norm_w,   // (256,40)
    const float* __restrict__ g_in_w,     // (256,160,40)
    const float* __restrict__ g_conv_w,   // (256,80,4)
    const float* __restrict__ g_conv_b,   // (256,80)
    const float* __restrict__ g_xp_w,     // (256,35,80)
    const float* __restrict__ g_dt_w,     // (256,80,3)
    const float* __restrict__ g_dt_b,     // (256,80)
    const float* __restrict__ g_alog,     // (256,80,16)
    const float* __restrict__ g_D,        // (256,80)
    const float* __restrict__ g_out_w,    // (256,40,80)
    float* __restrict__ xb0,
    float* __restrict__ xb1,
    int* __restrict__ flags)
{
  const int layer = blockIdx.x;
  const int tid = threadIdx.x;

  // activations only in LDS (~8 KB)
  __shared__ float xin[CH * 40];
  __shared__ float uu[CH * 40];
  __shared__ float xz[CH * 160];
  __shared__ float xs[CH * 80];
  __shared__ float dbc[CH * 36];    // stride 36 (35 outputs + pad)
  __shared__ float yb[CH * 80];
  __shared__ float xhist[240];      // conv tail: last 3 x-half tokens

  // ---------------- per-thread stationary weights (registers) --------------
  // in_proj: thread owns row e_in, computes tokens {tA, tA+2}
  const int e_in = tid % 160;
  const int tA = tid / 160;
  float w_in_r[40];
  {
    const float4* g = (const float4*)(g_in_w + layer * 6400 + e_in * 40);
#pragma unroll
    for (int k = 0; k < 10; ++k) {
      float4 v = g[k];
      w_in_r[4 * k] = v.x; w_in_r[4 * k + 1] = v.y;
      w_in_r[4 * k + 2] = v.z; w_in_r[4 * k + 3] = v.w;
    }
  }
  // rmsnorm weight (tid<160 uses it)
  const float nrmw = g_norm_w[layer * 40 + (tid % 40)];
  // conv: thread (t_c, d_c)
  const int d_c = tid % 80;
  const int t_c = tid / 80;
  float cw[4]; float cb;
  {
    float4 v = *(const float4*)(g_conv_w + layer * 320 + d_c * 4);
    cw[0] = v.x; cw[1] = v.y; cw[2] = v.z; cw[3] = v.w;
    cb = g_conv_b[layer * 80 + d_c];
  }
  // x_proj: pairs, tid<280: p=tid/2 -> (t_x, e_x), half-dot of 40
  const int halfp = tid & 1;
  const int p_x = tid >> 1;              // 0..159 (only <140 active)
  const int t_x = p_x / 35, e_x = p_x % 35;
  float w_xp_r[40];
  if (p_x < 140) {
    const float4* g = (const float4*)(g_xp_w + layer * 2800 + e_x * 80 + halfp * 40);
#pragma unroll
    for (int k = 0; k < 10; ++k) {
      float4 v = g[k];
      w_xp_r[4 * k] = v.x; w_xp_r[4 * k + 1] = v.y;
      w_xp_r[4 * k + 2] = v.z; w_xp_r[4 * k + 3] = v.w;
    }
  }
  // scan: thread (d_ch, qq) with state in regs
  const int d_ch = tid >> 2;
  const int qq = tid & 3;
  float negA[4], hst[4];
  {
    float4 v = *(const float4*)(g_alog + layer * 1280 + tid * 4);
    negA[0] = -__expf(v.x); negA[1] = -__expf(v.y);
    negA[2] = -__expf(v.z); negA[3] = -__expf(v.w);
    hst[0] = hst[1] = hst[2] = hst[3] = 0.f;
  }
  const float dtw0 = g_dt_w[layer * 240 + d_ch * 3 + 0];
  const float dtw1 = g_dt_w[layer * 240 + d_ch * 3 + 1];
  const float dtw2 = g_dt_w[layer * 240 + d_ch * 3 + 2];
  const float dtb = g_dt_b[layer * 80 + d_ch];
  const float wD = g_D[layer * 80 + d_ch];
  // out_proj: pairs, p=tid/2 -> (t_o, e_o), half-dot of 40
  const int p_o = tid >> 1;              // 0..159
  const int t_o = p_o / 40, e_o = p_o % 40;
  float w_out_r[40];
  {
    const float4* g = (const float4*)(g_out_w + layer * 3200 + e_o * 80 + halfp * 40);
#pragma unroll
    for (int k = 0; k < 10; ++k) {
      float4 v = g[k];
      w_out_r[4 * k] = v.x; w_out_r[4 * k + 1] = v.y;
      w_out_r[4 * k + 2] = v.z; w_out_r[4 * k + 3] = v.w;
    }
  }

  for (int i = tid; i < 240; i += TPB1) xhist[i] = 0.f;
  __syncthreads();

  float* xcur = (layer & 1) ? xb1 : xb0;
  const float* xprev = (layer & 1) ? xb0 : xb1;
  const float* src = (layer == 0) ? mash : xprev;
  int* flag_prev = flags + (layer - 1) * 16;
  int* flag_cur = flags + layer * 16;

  for (int c = 0; c < NCHUNK; ++c) {
    const int t0 = c * CH;
    // ---- wait for producer: single-thread relaxed poll, no fences ----
    if (layer > 0 && tid == 0) {
      while (__hip_atomic_load(flag_prev, __ATOMIC_RELAXED, __HIP_MEMORY_SCOPE_AGENT) <= c)
        __builtin_amdgcn_s_sleep(1);
    }
    __syncthreads();
    // ---- load residual chunk via IF$-coherent loads ----
    if (tid < CH * 40)
      xin[tid] = __hip_atomic_load(&src[t0 * 40 + tid], __ATOMIC_RELAXED,
                                   __HIP_MEMORY_SCOPE_AGENT);
    __syncthreads();
    // ---- rmsnorm (redundant sumsq per element; float4 broadcast reads) ----
    if (tid < CH * 40) {
      const int t = tid / 40;
      const float4* xp = (const float4*)&xin[t * 40];
      float ss = 0.f;
#pragma unroll
      for (int k = 0; k < 10; ++k) {
        float4 v = xp[k];
        ss += v.x * v.x + v.y * v.y + v.z * v.z + v.w * v.w;
      }
      uu[tid] = xin[tid] * rsqrtf(ss * (1.f / 40.f) + 1e-5f) * nrmw;
    }
    __syncthreads();
    // ---- in_proj: weights in regs, uu broadcast ----
#pragma unroll
    for (int tt = 0; tt < 2; ++tt) {
      const int t = tA + 2 * tt;
      const float4* up = (const float4*)&uu[t * 40];
      float s = 0.f;
#pragma unroll
      for (int k = 0; k < 10; ++k) {
        float4 v = up[k];
        s += w_in_r[4 * k] * v.x + w_in_r[4 * k + 1] * v.y
           + w_in_r[4 * k + 2] * v.z + w_in_r[4 * k + 3] * v.w;
      }
      xz[t * 160 + e_in] = s;
    }
    __syncthreads();
    // ---- causal depthwise conv(4) + silu (xhist holds pre-chunk zeros/tail) ----
    {
      float acc = cb;
#pragma unroll
      for (int j = 0; j < 4; ++j) {
        int lt = t_c - 3 + j;
        float xv = (lt >= 0) ? xz[lt * 160 + d_c] : xhist[(lt + 3) * 80 + d_c];
        acc += cw[j] * xv;
      }
      xs[t_c * 80 + d_c] = acc / (1.f + __expf(-acc));
    }
    __syncthreads();
    // ---- x_proj: pair half-dots + shfl merge; idle threads refresh xhist ----
    if (p_x < 140) {
      const float4* xp = (const float4*)&xs[t_x * 80 + halfp * 40];
      float s = 0.f;
#pragma unroll
      for (int k = 0; k < 10; ++k) {
        float4 v = xp[k];
        s += w_xp_r[4 * k] * v.x + w_xp_r[4 * k + 1] * v.y
           + w_xp_r[4 * k + 2] * v.z + w_xp_r[4 * k + 3] * v.w;
      }
      s += __shfl_xor(s, 1);
      if (halfp == 0) dbc[t_x * 36 + e_x] = s;
    } else {
      for (int k = tid - 280; k < 240; k += 40)
        xhist[k] = xz[(1 + k / 80) * 160 + (k % 80)];
    }
    __syncthreads();
    // ---- selective scan; dt inline; state in regs ----
#pragma unroll
    for (int t = 0; t < CH; ++t) {
      float sdt = dtb + dbc[t * 36 + 0] * dtw0 + dbc[t * 36 + 1] * dtw1
                      + dbc[t * 36 + 2] * dtw2;
      float dtval = (sdt > 20.f) ? sdt : log1pf(__expf(sdt));
      float xval = xs[t * 80 + d_ch];
      float part = 0.f;
#pragma unroll
      for (int j = 0; j < 4; ++j) {
        int s_i = qq * 4 + j;
        float Bv = dbc[t * 36 + 3 + s_i];
        float Cv = dbc[t * 36 + 19 + s_i];
        hst[j] = __expf(dtval * negA[j]) * hst[j] + dtval * Bv * xval;
        part += hst[j] * Cv;
      }
      part += __shfl_xor(part, 1);
      part += __shfl_xor(part, 2);
      if (qq == 0) {
        float yv = part + xval * wD;
        float z = xz[t * 160 + 80 + d_ch];
        yb[t * 80 + d_ch] = yv * z / (1.f + __expf(-z));
      }
    }
    __syncthreads();
    // ---- out_proj: pair half-dots + merge; residual; IF$ store ----
    {
      const float4* yp = (const float4*)&yb[t_o * 80 + halfp * 40];
      float s = 0.f;
#pragma unroll
      for (int k = 0; k < 10; ++k) {
        float4 v = yp[k];
        s += w_out_r[4 * k] * v.x + w_out_r[4 * k + 1] * v.y
           + w_out_r[4 * k + 2] * v.z + w_out_r[4 * k + 3] * v.w;
      }
      s += __shfl_xor(s, 1);
      if (halfp == 0)
        __hip_atomic_store(&xcur[t0 * 40 + p_o], xin[p_o] + s,
                           __ATOMIC_RELAXED, __HIP_MEMORY_SCOPE_AGENT);
    }
    // barrier drains every wave's vmcnt -> all stores acked at IF$
    __syncthreads();
    if (tid == 0)
      __hip_atomic_store(flag_cur, c + 1, __ATOMIC_RELAXED, __HIP_MEMORY_SCOPE_AGENT);
  }
}

// ---- context side of cross-attn: cn = LN(x_final), kv = cn @ ca_kv_w^T ----
__global__ __launch_bounds__(64) void kv_kernel(
    const float* __restrict__ xfin,
    const float* __restrict__ lnc_w, const float* __restrict__ lnc_b,
    const float* __restrict__ kv_w,
    float* __restrict__ kbuf, float* __restrict__ vbuf)
{
  int t = blockIdx.x;
  int lane = threadIdx.x;
  float x = (lane < 40) ? xfin[t * 40 + lane] : 0.f;
  float s = x;
#pragma unroll
  for (int o = 32; o >= 1; o >>= 1) s += __shfl_xor(s, o);
  float m = s * (1.f / 40.f);
  float dv = (lane < 40) ? (x - m) : 0.f;
  float v2 = dv * dv;
#pragma unroll
  for (int o = 32; o >= 1; o >>= 1) v2 += __shfl_xor(v2, o);
  float rstd = rsqrtf(v2 * (1.f / 40.f) + 1e-5f);
  __shared__ float cn[40];
  if (lane < 40) cn[lane] = dv * rstd * lnc_w[lane] + lnc_b[lane];
  __syncthreads();
  for (int e = lane; e < 80; e += 64) {
    float acc = 0.f;
#pragma unroll
    for (int d = 0; d < 40; ++d) acc += cn[d] * kv_w[e * 40 + d];
    if (e < 40) kbuf[t * 40 + e] = acc;
    else vbuf[t * 40 + (e - 40)] = acc;
  }
}

// ---- per-query decode: 2 threads/query, pair-split everywhere ----
__global__ __launch_bounds__(256) void query_kernel(
    const float* __restrict__ qry,
    const float* __restrict__ pe_w, const float* __restrict__ pe_b,
    const float* __restrict__ lnq_w, const float* __restrict__ lnq_b,
    const float* __restrict__ qw,
    const float* __restrict__ ow, const float* __restrict__ ob,
    const float* __restrict__ flw, const float* __restrict__ flb,
    const float* __restrict__ w1, const float* __restrict__ b1,
    const float* __restrict__ w2, const float* __restrict__ b2,
    const float* __restrict__ outw, const float* __restrict__ outb,
    const float* __restrict__ kbuf, const float* __restrict__ vbuf,
    float* __restrict__ out)
{
  const int tid = threadIdx.x;
  const int gid = blockIdx.x * 256 + tid;
  const int n = gid >> 1;          // query index
  const int h = gid & 1;           // pair half
  __shared__ float colbuf[40 * 256];  // per-thread 40-vec staging (own column)

  const float qx = qry[n * 3 + 0], qy = qry[n * 3 + 1], qz = qry[n * 3 + 2];

  // PE-MLP, split over frequency octaves (h*4..h*4+4), merged via shfl
  float qp[40];
#pragma unroll
  for (int d = 0; d < 40; ++d) qp[d] = 0.f;
#pragma unroll
  for (int jj = 0; jj < 4; ++jj) {
    const int j = h * 4 + jj;
    float f = 3.14159265358979323846f * (float)(1 << j);
    float sx, cx, sy, cy, sz, cz;
    __sincosf(qx * f, &sx, &cx);
    __sincosf(qy * f, &sy, &cy);
    __sincosf(qz * f, &sz, &cz);
#pragma unroll
    for (int d = 0; d < 40; ++d) {
      const float* r = pe_w + d * 51;
      qp[d] += sx * r[j] + sy * r[j + 8] + sz * r[j + 16]
             + cx * r[j + 24] + cy * r[j + 32] + cz * r[j + 40];
    }
  }
  float qe[40];
#pragma unroll
  for (int d = 0; d < 40; ++d) {
    const float* r = pe_w + d * 51;
    qe[d] = pe_b[d] + qp[d] + __shfl_xor(qp[d], 1)
          + qx * r[48] + qy * r[49] + qz * r[50];
  }

  // layernorm(qe) -> own LDS column (dynamic d index for the matvec)
  {
    float m = 0.f;
#pragma unroll
    for (int d = 0; d < 40; ++d) m += qe[d];
    m *= (1.f / 40.f);
    float var = 0.f;
#pragma unroll
    for (int d = 0; d < 40; ++d) { float dv = qe[d] - m; var += dv * dv; }
    float rstd = rsqrtf(var * (1.f / 40.f) + 1e-5f);
#pragma unroll
    for (int d = 0; d < 40; ++d)
      colbuf[d * 256 + tid] = (qe[d] - m) * rstd * lnq_w[d] + lnq_b[d];
  }

  // q = qn @ ca_q_w^T, split over d (h*20..h*20+20), merged via shfl
  float q[40];
#pragma unroll
  for (int e = 0; e < 40; ++e) q[e] = 0.f;
#pragma unroll 1
  for (int d = h * 20; d < h * 20 + 20; ++d) {
    float qv = colbuf[d * 256 + tid];
#pragma unroll
    for (int e = 0; e < 40; ++e) q[e] += qv * qw[e * 40 + d];
  }
#pragma unroll
  for (int e = 0; e < 40; ++e) q[e] += __shfl_xor(q[e], 1);

  // online-softmax attention over this thread's 200 context tokens (float4)
  float acc[40];
#pragma unroll
  for (int d = 0; d < 40; ++d) acc[d] = 0.f;
  float mx = -1e30f, l = 0.f;
  const float scale = 0.15811388300841897f;  // 40^-0.5
  const int tbeg = h * 200, tend = tbeg + 200;
#pragma unroll 1
  for (int t = tbeg; t < tend; ++t) {
    const float4* kr = (const float4*)(kbuf + t * 40);
    float s0 = 0.f, s1 = 0.f, s2 = 0.f, s3 = 0.f;
#pragma unroll
    for (int k = 0; k < 10; ++k) {
      float4 k4 = kr[k];
      s0 += q[4 * k] * k4.x; s1 += q[4 * k + 1] * k4.y;
      s2 += q[4 * k + 2] * k4.z; s3 += q[4 * k + 3] * k4.w;
    }
    float s = ((s0 + s1) + (s2 + s3)) * scale;
    if (s > mx) {
      float corr = __expf(mx - s);
      l *= corr;
#pragma unroll
      for (int d = 0; d < 40; ++d) acc[d] *= corr;
      mx = s;
    }
    float p = __expf(s - mx);
    l += p;
    const float4* vr = (const float4*)(vbuf + t * 40);
#pragma unroll
    for (int k = 0; k < 10; ++k) {
      float4 v4 = vr[k];
      acc[4 * k] += p * v4.x; acc[4 * k + 1] += p * v4.y;
      acc[4 * k + 2] += p * v4.z; acc[4 * k + 3] += p * v4.w;
    }
  }
  // merge halves across the lane pair (both lanes end with the full result)
  {
    float m2 = __shfl_xor(mx, 1);
    float l2 = __shfl_xor(l, 1);
    float nm = fmaxf(mx, m2);
    float a = __expf(mx - nm), b = __expf(m2 - nm);
    l = l * a + l2 * b;
#pragma unroll
    for (int d = 0; d < 40; ++d)
      acc[d] = acc[d] * a + __shfl_xor(acc[d], 1) * b;
  }
  float linv = 1.f / l;
#pragma unroll
  for (int d = 0; d < 40; ++d) colbuf[d * 256 + tid] = acc[d] * linv;

  // lat2 = lat @ ca_out_w^T + ob, split over d, merged via shfl
  float lp[40];
#pragma unroll
  for (int e = 0; e < 40; ++e) lp[e] = 0.f;
#pragma unroll 1
  for (int d = h * 20; d < h * 20 + 20; ++d) {
    float lv = colbuf[d * 256 + tid];
#pragma unroll
    for (int e = 0; e < 40; ++e) lp[e] += lv * ow[e * 40 + d];
  }
  float lat2[40];
#pragma unroll
  for (int e = 0; e < 40; ++e) lat2[e] = ob[e] + lp[e] + __shfl_xor(lp[e], 1);

  // h = LN(lat2)
  float hh[40];
  {
    float m = 0.f;
#pragma unroll
    for (int d = 0; d < 40; ++d) m += lat2[d];
    m *= (1.f / 40.f);
    float var = 0.f;
#pragma unroll
    for (int d = 0; d < 40; ++d) { float dv = lat2[d] - m; var += dv * dv; }
    float rstd = rsqrtf(var * (1.f / 40.f) + 1e-5f);
#pragma unroll
    for (int d = 0; d < 40; ++d) hh[d] = (lat2[d] - m) * rstd * flw[d] + flb[d];
  }

  // FFN: split e over halves (h*80..h*80+80), merge ff via shfl
  float ff[40];
#pragma unroll
  for (int d = 0; d < 40; ++d) ff[d] = 0.f;
#pragma unroll 1
  for (int e = h * 80; e < h * 80 + 80; ++e) {
    const float* r1 = w1 + e * 40;
    const float* r2 = w1 + (160 + e) * 40;
    float a0 = 0.f, a1 = 0.f;
#pragma unroll
    for (int d = 0; d < 40; ++d) { a0 += hh[d] * r1[d]; a1 += hh[d] * r2[d]; }
    float x1 = a0 + b1[e];
    float g = a1 + b1[160 + e];
    float tv = x1 * (0.5f * g * (1.f + erff(g * 0.70710678118654752f)));
#pragma unroll
    for (int d = 0; d < 40; ++d) ff[d] += tv * w2[d * 160 + e];
  }
  float r = outb[0];
#pragma unroll
  for (int d = 0; d < 40; ++d) {
    float f = ff[d] + __shfl_xor(ff[d], 1) + b2[d];
    r += (lat2[d] + f) * outw[d];
  }
  if (h == 0) out[n] = r;
}

extern "C" void kernel_launch(void* const* d_in, const int* in_sizes, int n_in,
                              void* d_out, int out_size, void* d_ws, size_t ws_size,
                              hipStream_t stream) {
  const float* mash   = (const float*)d_in[0];
  const float* qry    = (const float*)d_in[1];
  const float* lnw    = (const float*)d_in[2];
  const float* linw   = (const float*)d_in[3];
  const float* lconvw = (const float*)d_in[4];
  const float* lconvb = (const float*)d_in[5];
  const float* lxpw   = (const float*)d_in[6];
  const float* ldtw   = (const float*)d_in[7];
  const float* ldtb   = (const float*)d_in[8];
  const float* lAlog  = (const float*)d_in[9];
  const float* lD     = (const float*)d_in[10];
  const float* loutw  = (const float*)d_in[11];
  const float* pew    = (const float*)d_in[12];
  const float* peb    = (const float*)d_in[13];
  const float* lnqw   = (const float*)d_in[14];
  const float* lnqb   = (const float*)d_in[15];
  const float* lncw   = (const float*)d_in[16];
  const float* lncb   = (const float*)d_in[17];
  const float* qw     = (const float*)d_in[18];
  const float* kvw    = (const float*)d_in[19];
  const float* oww    = (const float*)d_in[20];
  const float* owb    = (const float*)d_in[21];
  const float* flnw   = (const float*)d_in[22];
  const float* flnb   = (const float*)d_in[23];
  const float* w1     = (const float*)d_in[24];
  const float* b1     = (const float*)d_in[25];
  const float* w2     = (const float*)d_in[26];
  const float* b2     = (const float*)d_in[27];
  const float* outw   = (const float*)d_in[28];
  const float* outb   = (const float*)d_in[29];

  // ws layout (f32 elements): xb0[16000] xb1[16000] k[16000] v[16000] flags
  float* wsf = (float*)d_ws;
  float* xb0 = wsf;
  float* xb1 = wsf + 16000;
  float* kbuf = wsf + 32000;
  float* vbuf = wsf + 48000;
  int* flags = (int*)(wsf + 64000);

  hipLaunchKernelGGL(init_flags, dim3(16), dim3(256), 0, stream, flags);
  hipLaunchKernelGGL(mamba_pipe, dim3(256), dim3(TPB1), 0, stream,
                     mash, lnw, linw, lconvw, lconvb, lxpw, ldtw, ldtb, lAlog,
                     lD, loutw, xb0, xb1, flags);
  // layer 255 writes xb1 ((255&1)==1)
  hipLaunchKernelGGL(kv_kernel, dim3(400), dim3(64), 0, stream,
                     xb1, lncw, lncb, kvw, kbuf, vbuf);
  hipLaunchKernelGGL(query_kernel, dim3(512), dim3(256), 0, stream,
                     qry, pew, peb, lnqw, lnqb, qw, oww, owb, flnw, flnb,
                     w1, b1, w2, b2, outw, outb, kbuf, vbuf, (float*)d_out);
}

// Round 4
// 2468.193 us; speedup vs baseline: 1.9681x; 1.1956x over previous
//
#include <hip/hip_runtime.h>

// ---------------------------------------------------------------------------
// MashDecoderV2: 256-layer mamba stack (L=400, D=40) + 65536-query cross-attn
// decoder. f32 throughout (threshold 1.56e-2; current absmax 2e-3).
//
// Stage 1: layer-pipelined persistent kernel, 1 WG/layer, 320 threads.
//   All handoff data/flags via relaxed AGENT-scope atomics (sc0+sc1: bypass
//   L1/L2, coherent at IF$) - correct under any workgroup->XCD mapping, no
//   L2 writeback/invalidate storms. Round-4 changes:
//   - every wave polls the producer flag itself (no post-poll barrier)
//   - SPECULATIVE chunk loads: data loads issue alongside the flag check;
//     steady-state producer is ahead so latencies overlap (slow path reloads)
//   - rmsnorm folded into in_proj (norm_w pre-multiplied into stationary
//     weight regs; per-token sumsq from registers) - phase + barrier removed
//   - 5 barriers/chunk (was 8)
// Stage 2: round-2 query kernel (measured best) + float4 k/v loads.
// ---------------------------------------------------------------------------

#define CH 4
#define NCHUNK 100       // 400 / CH
#define TPB1 320

__global__ void init_flags(int* __restrict__ flags) {
  int i = blockIdx.x * 256 + threadIdx.x;
  if (i < 256 * 16) flags[i] = 0;
}

__global__ __launch_bounds__(TPB1) void mamba_pipe(
    const float* __restrict__ mash,
    const float* __restrict__ g_norm_w,   // (256,40)
    const float* __restrict__ g_in_w,     // (256,160,40)
    const float* __restrict__ g_conv_w,   // (256,80,4)
    const float* __restrict__ g_conv_b,   // (256,80)
    const float* __restrict__ g_xp_w,     // (256,35,80)
    const float* __restrict__ g_dt_w,     // (256,80,3)
    const float* __restrict__ g_dt_b,     // (256,80)
    const float* __restrict__ g_alog,     // (256,80,16)
    const float* __restrict__ g_D,        // (256,80)
    const float* __restrict__ g_out_w,    // (256,40,80)
    float* __restrict__ xb0,
    float* __restrict__ xb1,
    int* __restrict__ flags)
{
  const int layer = blockIdx.x;
  const int tid = threadIdx.x;

  // activations only in LDS (~7 KB)
  __shared__ float xin[CH * 40];    // residual copy for out_proj
  __shared__ float xz[CH * 160];
  __shared__ float xs[CH * 80];
  __shared__ float dbc[CH * 36];    // stride 36 (35 outputs + pad)
  __shared__ float yb[CH * 80];
  __shared__ float xhist[240];      // conv tail: last 3 x-half tokens

  // ---------------- per-thread stationary weights (registers) --------------
  // in_proj: thread owns row e_in with norm_w folded in; tokens {tA, tA+2}
  const int e_in = tid % 160;
  const int tA = tid / 160;
  float w_in_r[40];
  {
    const float4* g = (const float4*)(g_in_w + layer * 6400 + e_in * 40);
    const float4* nw = (const float4*)(g_norm_w + layer * 40);
#pragma unroll
    for (int k = 0; k < 10; ++k) {
      float4 v = g[k];
      float4 n = nw[k];
      w_in_r[4 * k] = v.x * n.x; w_in_r[4 * k + 1] = v.y * n.y;
      w_in_r[4 * k + 2] = v.z * n.z; w_in_r[4 * k + 3] = v.w * n.w;
    }
  }
  // conv: thread (t_c, d_c)
  const int d_c = tid % 80;
  const int t_c = tid / 80;
  float cw[4]; float cb;
  {
    float4 v = *(const float4*)(g_conv_w + layer * 320 + d_c * 4);
    cw[0] = v.x; cw[1] = v.y; cw[2] = v.z; cw[3] = v.w;
    cb = g_conv_b[layer * 80 + d_c];
  }
  // x_proj: pairs, p=tid/2 -> (t_x, e_x), half-dot of 40
  const int halfp = tid & 1;
  const int p_x = tid >> 1;              // only <140 active
  const int t_x = p_x / 35, e_x = p_x % 35;
  float w_xp_r[40];
  if (p_x < 140) {
    const float4* g = (const float4*)(g_xp_w + layer * 2800 + e_x * 80 + halfp * 40);
#pragma unroll
    for (int k = 0; k < 10; ++k) {
      float4 v = g[k];
      w_xp_r[4 * k] = v.x; w_xp_r[4 * k + 1] = v.y;
      w_xp_r[4 * k + 2] = v.z; w_xp_r[4 * k + 3] = v.w;
    }
  }
  // scan: thread (d_ch, qq) with state in regs
  const int d_ch = tid >> 2;
  const int qq = tid & 3;
  float negA[4], hst[4];
  {
    float4 v = *(const float4*)(g_alog + layer * 1280 + tid * 4);
    negA[0] = -__expf(v.x); negA[1] = -__expf(v.y);
    negA[2] = -__expf(v.z); negA[3] = -__expf(v.w);
    hst[0] = hst[1] = hst[2] = hst[3] = 0.f;
  }
  const float dtw0 = g_dt_w[layer * 240 + d_ch * 3 + 0];
  const float dtw1 = g_dt_w[layer * 240 + d_ch * 3 + 1];
  const float dtw2 = g_dt_w[layer * 240 + d_ch * 3 + 2];
  const float dtb = g_dt_b[layer * 80 + d_ch];
  const float wD = g_D[layer * 80 + d_ch];
  // out_proj: pairs, p=tid/2 -> (t_o, e_o), half-dot of 40
  const int p_o = tid >> 1;
  const int t_o = p_o / 40, e_o = p_o % 40;
  float w_out_r[40];
  {
    const float4* g = (const float4*)(g_out_w + layer * 3200 + e_o * 80 + halfp * 40);
#pragma unroll
    for (int k = 0; k < 10; ++k) {
      float4 v = g[k];
      w_out_r[4 * k] = v.x; w_out_r[4 * k + 1] = v.y;
      w_out_r[4 * k + 2] = v.z; w_out_r[4 * k + 3] = v.w;
    }
  }

  for (int i = tid; i < 240; i += TPB1) xhist[i] = 0.f;
  __syncthreads();

  float* xcur = (layer & 1) ? xb1 : xb0;
  const float* xprev = (layer & 1) ? xb0 : xb1;
  const float* src = (layer == 0) ? mash : xprev;
  int* flag_prev = flags + (layer - 1) * 16;
  int* flag_cur = flags + layer * 16;

  for (int c = 0; c < NCHUNK; ++c) {
    const int t0 = c * CH;

    // ---- Phase A: speculative poll + direct global loads + in_proj ----
    // Every wave checks the flag itself (wave-uniform). Data loads issue in
    // parallel with the check; if the producer wasn't ahead, spin and reload.
    bool ready = (layer == 0);
    if (!ready)
      ready = __hip_atomic_load(flag_prev, __ATOMIC_RELAXED,
                                __HIP_MEMORY_SCOPE_AGENT) > c;
    float xzv[2];
    float xi = 0.f;
    for (;;) {
#pragma unroll
      for (int tt = 0; tt < 2; ++tt) {
        const int t = tA + 2 * tt;
        const float* sp = src + (t0 + t) * 40;
        float x[40];
#pragma unroll
        for (int d = 0; d < 40; ++d)
          x[d] = __hip_atomic_load(sp + d, __ATOMIC_RELAXED,
                                   __HIP_MEMORY_SCOPE_AGENT);
        float ss = 0.f;
#pragma unroll
        for (int d = 0; d < 40; ++d) ss += x[d] * x[d];
        float rs = rsqrtf(ss * (1.f / 40.f) + 1e-5f);
        float s = 0.f;
#pragma unroll
        for (int d = 0; d < 40; ++d) s += w_in_r[d] * x[d];
        xzv[tt] = s * rs;
      }
      if (tid < 160)
        xi = __hip_atomic_load(src + t0 * 40 + tid, __ATOMIC_RELAXED,
                               __HIP_MEMORY_SCOPE_AGENT);
      if (ready) break;
      while (__hip_atomic_load(flag_prev, __ATOMIC_RELAXED,
                               __HIP_MEMORY_SCOPE_AGENT) <= c)
        __builtin_amdgcn_s_sleep(2);
      ready = true;
    }
    xz[tA * 160 + e_in] = xzv[0];
    xz[(tA + 2) * 160 + e_in] = xzv[1];
    if (tid < 160) xin[tid] = xi;
    __syncthreads();                                    // B1: xz, xin ready

    // ---- causal depthwise conv(4) + silu ----
    {
      float acc = cb;
#pragma unroll
      for (int j = 0; j < 4; ++j) {
        int lt = t_c - 3 + j;
        float xv = (lt >= 0) ? xz[lt * 160 + d_c] : xhist[(lt + 3) * 80 + d_c];
        acc += cw[j] * xv;
      }
      xs[t_c * 80 + d_c] = acc / (1.f + __expf(-acc));
    }
    __syncthreads();                                    // B2: xs ready

    // ---- x_proj: pair half-dots + shfl merge; idle threads refresh xhist ----
    if (p_x < 140) {
      const float4* xp = (const float4*)&xs[t_x * 80 + halfp * 40];
      float s = 0.f;
#pragma unroll
      for (int k = 0; k < 10; ++k) {
        float4 v = xp[k];
        s += w_xp_r[4 * k] * v.x + w_xp_r[4 * k + 1] * v.y
           + w_xp_r[4 * k + 2] * v.z + w_xp_r[4 * k + 3] * v.w;
      }
      s += __shfl_xor(s, 1);
      if (halfp == 0) dbc[t_x * 36 + e_x] = s;
    } else {
      for (int k = tid - 280; k < 240; k += 40)
        xhist[k] = xz[(1 + k / 80) * 160 + (k % 80)];
    }
    __syncthreads();                                    // B3: dbc ready

    // ---- selective scan; dt inline; state in regs ----
#pragma unroll
    for (int t = 0; t < CH; ++t) {
      float sdt = dtb + dbc[t * 36 + 0] * dtw0 + dbc[t * 36 + 1] * dtw1
                      + dbc[t * 36 + 2] * dtw2;
      float dtval = (sdt > 15.f) ? sdt : __logf(1.f + __expf(sdt));
      float xval = xs[t * 80 + d_ch];
      float part = 0.f;
#pragma unroll
      for (int j = 0; j < 4; ++j) {
        int s_i = qq * 4 + j;
        float Bv = dbc[t * 36 + 3 + s_i];
        float Cv = dbc[t * 36 + 19 + s_i];
        hst[j] = __expf(dtval * negA[j]) * hst[j] + dtval * Bv * xval;
        part += hst[j] * Cv;
      }
      part += __shfl_xor(part, 1);
      part += __shfl_xor(part, 2);
      if (qq == 0) {
        float yv = part + xval * wD;
        float z = xz[t * 160 + 80 + d_ch];
        yb[t * 80 + d_ch] = yv * z / (1.f + __expf(-z));
      }
    }
    __syncthreads();                                    // B4: yb ready

    // ---- out_proj: pair half-dots + merge; residual; IF$ store ----
    {
      const float4* yp = (const float4*)&yb[t_o * 80 + halfp * 40];
      float s = 0.f;
#pragma unroll
      for (int k = 0; k < 10; ++k) {
        float4 v = yp[k];
        s += w_out_r[4 * k] * v.x + w_out_r[4 * k + 1] * v.y
           + w_out_r[4 * k + 2] * v.z + w_out_r[4 * k + 3] * v.w;
      }
      s += __shfl_xor(s, 1);
      if (halfp == 0)
        __hip_atomic_store(&xcur[t0 * 40 + p_o], xin[p_o] + s,
                           __ATOMIC_RELAXED, __HIP_MEMORY_SCOPE_AGENT);
    }
    // B5: drains every wave's vmcnt -> all stores acked at IF$
    __syncthreads();
    if (tid == 0)
      __hip_atomic_store(flag_cur, c + 1, __ATOMIC_RELAXED, __HIP_MEMORY_SCOPE_AGENT);
  }
}

// ---- context side of cross-attn: cn = LN(x_final), kv = cn @ ca_kv_w^T ----
__global__ __launch_bounds__(64) void kv_kernel(
    const float* __restrict__ xfin,
    const float* __restrict__ lnc_w, const float* __restrict__ lnc_b,
    const float* __restrict__ kv_w,
    float* __restrict__ kbuf, float* __restrict__ vbuf)
{
  int t = blockIdx.x;
  int lane = threadIdx.x;
  float x = (lane < 40) ? xfin[t * 40 + lane] : 0.f;
  float s = x;
#pragma unroll
  for (int o = 32; o >= 1; o >>= 1) s += __shfl_xor(s, o);
  float m = s * (1.f / 40.f);
  float dv = (lane < 40) ? (x - m) : 0.f;
  float v2 = dv * dv;
#pragma unroll
  for (int o = 32; o >= 1; o >>= 1) v2 += __shfl_xor(v2, o);
  float rstd = rsqrtf(v2 * (1.f / 40.f) + 1e-5f);
  __shared__ float cn[40];
  if (lane < 40) cn[lane] = dv * rstd * lnc_w[lane] + lnc_b[lane];
  __syncthreads();
  for (int e = lane; e < 80; e += 64) {
    float acc = 0.f;
#pragma unroll
    for (int d = 0; d < 40; ++d) acc += cn[d] * kv_w[e * 40 + d];
    if (e < 40) kbuf[t * 40 + e] = acc;
    else vbuf[t * 40 + (e - 40)] = acc;
  }
}

// ---- per-query decode (round-2 structure + float4 k/v loads) ----
__global__ __launch_bounds__(256) void query_kernel(
    const float* __restrict__ qry,
    const float* __restrict__ pe_w, const float* __restrict__ pe_b,
    const float* __restrict__ lnq_w, const float* __restrict__ lnq_b,
    const float* __restrict__ qw,
    const float* __restrict__ ow, const float* __restrict__ ob,
    const float* __restrict__ flw, const float* __restrict__ flb,
    const float* __restrict__ w1, const float* __restrict__ b1,
    const float* __restrict__ w2, const float* __restrict__ b2,
    const float* __restrict__ outw, const float* __restrict__ outb,
    const float* __restrict__ kbuf, const float* __restrict__ vbuf,
    float* __restrict__ out)
{
  const int tid = threadIdx.x;
  const int gid = blockIdx.x * 256 + tid;
  const int n = gid >> 1;          // query index
  const int h = gid & 1;           // which half of the 400 tokens
  __shared__ float vbufA[40 * 256];   // per-thread 40-vec staging (own column)

  const float qx = qry[n * 3 + 0], qy = qry[n * 3 + 1], qz = qry[n * 3 + 2];

  // positional-encoding MLP: qe[d] = pe_b[d] + sum_f pe[f]*W[d][f]
  float qe[40];
#pragma unroll
  for (int d = 0; d < 40; ++d) qe[d] = pe_b[d];
#pragma unroll 1
  for (int j = 0; j < 8; ++j) {
    float f = 3.14159265358979323846f * (float)(1 << j);
    float sx, cx, sy, cy, sz, cz;
    __sincosf(qx * f, &sx, &cx);
    __sincosf(qy * f, &sy, &cy);
    __sincosf(qz * f, &sz, &cz);
#pragma unroll
    for (int d = 0; d < 40; ++d) {
      const float* r = pe_w + d * 51;
      qe[d] += sx * r[j] + sy * r[j + 8] + sz * r[j + 16]
             + cx * r[j + 24] + cy * r[j + 32] + cz * r[j + 40];
    }
  }
#pragma unroll
  for (int d = 0; d < 40; ++d) {
    const float* r = pe_w + d * 51;
    qe[d] += qx * r[48] + qy * r[49] + qz * r[50];
  }

  // layernorm(qe) -> own LDS column (dynamic d index for the matvec)
  {
    float m = 0.f;
#pragma unroll
    for (int d = 0; d < 40; ++d) m += qe[d];
    m *= (1.f / 40.f);
    float var = 0.f;
#pragma unroll
    for (int d = 0; d < 40; ++d) { float dv = qe[d] - m; var += dv * dv; }
    float rstd = rsqrtf(var * (1.f / 40.f) + 1e-5f);
#pragma unroll
    for (int d = 0; d < 40; ++d)
      vbufA[d * 256 + tid] = (qe[d] - m) * rstd * lnq_w[d] + lnq_b[d];
  }

  // q = qn @ ca_q_w^T   (q in regs for the flash loop)
  float q[40];
#pragma unroll
  for (int e = 0; e < 40; ++e) q[e] = 0.f;
#pragma unroll 1
  for (int d = 0; d < 40; ++d) {
    float qv = vbufA[d * 256 + tid];
#pragma unroll
    for (int e = 0; e < 40; ++e) q[e] += qv * qw[e * 40 + d];
  }

  // online-softmax attention over this thread's 200 context tokens (float4)
  float acc[40];
#pragma unroll
  for (int d = 0; d < 40; ++d) acc[d] = 0.f;
  float mx = -1e30f, l = 0.f;
  const float scale = 0.15811388300841897f;  // 40^-0.5
  const int tbeg = h * 200, tend = tbeg + 200;
#pragma unroll 1
  for (int t = tbeg; t < tend; ++t) {
    const float4* kr = (const float4*)(kbuf + t * 40);
    float s0 = 0.f, s1 = 0.f, s2 = 0.f, s3 = 0.f;
#pragma unroll
    for (int k = 0; k < 10; ++k) {
      float4 k4 = kr[k];
      s0 += q[4 * k] * k4.x; s1 += q[4 * k + 1] * k4.y;
      s2 += q[4 * k + 2] * k4.z; s3 += q[4 * k + 3] * k4.w;
    }
    float s = ((s0 + s1) + (s2 + s3)) * scale;
    if (s > mx) {
      float corr = __expf(mx - s);
      l *= corr;
#pragma unroll
      for (int d = 0; d < 40; ++d) acc[d] *= corr;
      mx = s;
    }
    float p = __expf(s - mx);
    l += p;
    const float4* vr = (const float4*)(vbuf + t * 40);
#pragma unroll
    for (int k = 0; k < 10; ++k) {
      float4 v4 = vr[k];
      acc[4 * k] += p * v4.x; acc[4 * k + 1] += p * v4.y;
      acc[4 * k + 2] += p * v4.z; acc[4 * k + 3] += p * v4.w;
    }
  }
  // merge the two halves across the lane pair (both lanes get full result)
  {
    float m2 = __shfl_xor(mx, 1);
    float l2 = __shfl_xor(l, 1);
    float nm = fmaxf(mx, m2);
    float a = __expf(mx - nm), b = __expf(m2 - nm);
    l = l * a + l2 * b;
#pragma unroll
    for (int d = 0; d < 40; ++d)
      acc[d] = acc[d] * a + __shfl_xor(acc[d], 1) * b;
  }
  float linv = 1.f / l;
#pragma unroll
  for (int d = 0; d < 40; ++d) vbufA[d * 256 + tid] = acc[d] * linv;

  // lat2 = lat @ ca_out_w^T + ob   (redundant per pair; no divergence)
  float lat2[40];
#pragma unroll
  for (int e = 0; e < 40; ++e) lat2[e] = ob[e];
#pragma unroll 1
  for (int d = 0; d < 40; ++d) {
    float lv = vbufA[d * 256 + tid];
#pragma unroll
    for (int e = 0; e < 40; ++e) lat2[e] += lv * ow[e * 40 + d];
  }

  // h = LN(lat2)
  float hh[40];
  {
    float m = 0.f;
#pragma unroll
    for (int d = 0; d < 40; ++d) m += lat2[d];
    m *= (1.f / 40.f);
    float var = 0.f;
#pragma unroll
    for (int d = 0; d < 40; ++d) { float dv = lat2[d] - m; var += dv * dv; }
    float rstd = rsqrtf(var * (1.f / 40.f) + 1e-5f);
#pragma unroll
    for (int d = 0; d < 40; ++d) hh[d] = (lat2[d] - m) * rstd * flw[d] + flb[d];
  }

  // FFN: split-GLU, exact-erf gelu
  float ff[40];
#pragma unroll
  for (int d = 0; d < 40; ++d) ff[d] = b2[d];
#pragma unroll 1
  for (int e = 0; e < 160; ++e) {
    const float* r1 = w1 + e * 40;
    const float* r2 = w1 + (160 + e) * 40;
    float a0 = 0.f, a1 = 0.f;
#pragma unroll
    for (int d = 0; d < 40; ++d) { a0 += hh[d] * r1[d]; a1 += hh[d] * r2[d]; }
    float x1 = a0 + b1[e];
    float g = a1 + b1[160 + e];
    float tv = x1 * (0.5f * g * (1.f + erff(g * 0.70710678118654752f)));
#pragma unroll
    for (int d = 0; d < 40; ++d) ff[d] += tv * w2[d * 160 + e];
  }

  float r = outb[0];
#pragma unroll
  for (int d = 0; d < 40; ++d) r += (lat2[d] + ff[d]) * outw[d];
  if (h == 0) out[n] = r;
}

extern "C" void kernel_launch(void* const* d_in, const int* in_sizes, int n_in,
                              void* d_out, int out_size, void* d_ws, size_t ws_size,
                              hipStream_t stream) {
  const float* mash   = (const float*)d_in[0];
  const float* qry    = (const float*)d_in[1];
  const float* lnw    = (const float*)d_in[2];
  const float* linw   = (const float*)d_in[3];
  const float* lconvw = (const float*)d_in[4];
  const float* lconvb = (const float*)d_in[5];
  const float* lxpw   = (const float*)d_in[6];
  const float* ldtw   = (const float*)d_in[7];
  const float* ldtb   = (const float*)d_in[8];
  const float* lAlog  = (const float*)d_in[9];
  const float* lD     = (const float*)d_in[10];
  const float* loutw  = (const float*)d_in[11];
  const float* pew    = (const float*)d_in[12];
  const float* peb    = (const float*)d_in[13];
  const float* lnqw   = (const float*)d_in[14];
  const float* lnqb   = (const float*)d_in[15];
  const float* lncw   = (const float*)d_in[16];
  const float* lncb   = (const float*)d_in[17];
  const float* qw     = (const float*)d_in[18];
  const float* kvw    = (const float*)d_in[19];
  const float* oww    = (const float*)d_in[20];
  const float* owb    = (const float*)d_in[21];
  const float* flnw   = (const float*)d_in[22];
  const float* flnb   = (const float*)d_in[23];
  const float* w1     = (const float*)d_in[24];
  const float* b1     = (const float*)d_in[25];
  const float* w2     = (const float*)d_in[26];
  const float* b2     = (const float*)d_in[27];
  const float* outw   = (const float*)d_in[28];
  const float* outb   = (const float*)d_in[29];

  // ws layout (f32 elements): xb0[16000] xb1[16000] k[16000] v[16000] flags
  float* wsf = (float*)d_ws;
  float* xb0 = wsf;
  float* xb1 = wsf + 16000;
  float* kbuf = wsf + 32000;
  float* vbuf = wsf + 48000;
  int* flags = (int*)(wsf + 64000);

  hipLaunchKernelGGL(init_flags, dim3(16), dim3(256), 0, stream, flags);
  hipLaunchKernelGGL(mamba_pipe, dim3(256), dim3(TPB1), 0, stream,
                     mash, lnw, linw, lconvw, lconvb, lxpw, ldtw, ldtb, lAlog,
                     lD, loutw, xb0, xb1, flags);
  // layer 255 writes xb1 ((255&1)==1)
  hipLaunchKernelGGL(kv_kernel, dim3(400), dim3(64), 0, stream,
                     xb1, lncw, lncb, kvw, kbuf, vbuf);
  hipLaunchKernelGGL(query_kernel, dim3(512), dim3(256), 0, stream,
                     qry, pew, peb, lnqw, lnqb, qw, oww, owb, flnw, flnb,
                     w1, b1, w2, b2, outw, outb, kbuf, vbuf, (float*)d_out);
}